// Round 7
// baseline (10937.947 us; speedup 1.0000x reference)
//
#include <hip/hip_runtime.h>
#include <stdint.h>

#define CDIM   4096
#define S_N    3355443
#define R_N    1048576
#define N1     (S_N + R_N)                 // 4404019 contributions
#define TILE   4096
#define WPT    (TILE / 256)                // 16 elements per thread
#define NTILES ((N1 + TILE - 1) / TILE)    // 1076
#define NPAD   (NTILES * TILE)             // 4407296
#define NSB    (NPAD / 256)                // 17216
#define PAD_KEY 0xFFFFFFu
#define PAD_VAL 0xFFFFFFFFu                // impossible value bits (sums are >= +0)
#define SENT  (((uint64_t)PAD_KEY << 32) | (uint64_t)PAD_VAL)
#define ADJF  ((float)(1.0 - (3355443.0 / 16777216.0) * (1.0 - 0.95)))

// Exclusive block-wide scan over 256 threads (4 waves). Contains syncthreads.
static __device__ __forceinline__ unsigned blockScanExcl(unsigned v, unsigned t,
                                                         unsigned* lw, unsigned* tot){
  unsigned lane = t & 63u, w = t >> 6;
  unsigned x = v;
  #pragma unroll
  for (int off = 1; off < 64; off <<= 1){
    unsigned y = __shfl_up(x, off, 64);
    if (lane >= (unsigned)off) x += y;
  }
  if (lane == 63u) lw[w] = x;
  __syncthreads();
  unsigned woff = 0;
  for (unsigned i = 0; i < w; i++) woff += lw[i];
  *tot = lw[0] + lw[1] + lw[2] + lw[3];
  __syncthreads();
  return x + woff - v;
}

// ---- decoupled lookback (pattern HW-validated in r5) ----------------------
// lb word: [31:28] pass tag (1..8), [27:26] status (1=aggregate, 2=inclusive),
// [25:0] count. Tag mismatch == unpublished (stale entries from earlier passes
// or the initial zero read as invalid), so ONE buffer serves all 8 passes.
static __device__ __forceinline__ void lb_publish(unsigned* __restrict__ lb,
                                                  unsigned b, unsigned t,
                                                  unsigned cnt, unsigned tag){
  unsigned st = (b == 0u) ? 2u : 1u;
  __hip_atomic_store(&lb[(size_t)b*256u + t], (tag<<28)|(st<<26)|cnt,
                     __ATOMIC_RELEASE, __HIP_MEMORY_SCOPE_AGENT);
}
static __device__ __forceinline__ unsigned lb_walk(unsigned* __restrict__ lb,
                                                   unsigned b, unsigned t,
                                                   unsigned cnt, unsigned tag){
  unsigned excl = 0u;
  if (b > 0u){
    int p = (int)b - 1;
    for (;;){
      unsigned v = __hip_atomic_load(&lb[(size_t)p*256u + t],
                                     __ATOMIC_ACQUIRE, __HIP_MEMORY_SCOPE_AGENT);
      if ((v >> 28) != tag){ __builtin_amdgcn_s_sleep(2); continue; }
      excl += v & 0x03FFFFFFu;
      if (((v >> 26) & 3u) == 2u) break;
      p--;
    }
    __hip_atomic_store(&lb[(size_t)b*256u + t], (tag<<28)|(2u<<26)|(excl + cnt),
                       __ATOMIC_RELEASE, __HIP_MEMORY_SCOPE_AGENT);
  }
  return excl;
}

// Recompute element i of the contribution array from the raw inputs.
// Samples first, then decayed buffer entries, then padding -> stable sort
// preserves segment_sum's accumulation order exactly.
static __device__ __forceinline__ uint64_t make_elem(unsigned i,
                                                     const int* __restrict__ sidx,
                                                     const int* __restrict__ ridx,
                                                     const float* __restrict__ rval,
                                                     const float* __restrict__ grad){
  uint32_t key, vb;
  if (i < S_N){
    key = (uint32_t)sidx[i];
    vb  = __float_as_uint(fabsf(grad[i]));
  } else if (i < N1){
    unsigned j = i - S_N;
    int2 rc = ((const int2* __restrict__)ridx)[j];
    key = (uint32_t)(rc.x * CDIM + rc.y);
    vb = __float_as_uint(ADJF * rval[j]);
  } else {
    key = PAD_KEY; vb = PAD_VAL;
  }
  return ((uint64_t)key << 32) | (uint64_t)vb;
}

// Upfront: per-tile hists of ALL THREE key bytes from the raw inputs (dense
// u16 writes, no global atomics) + zero the lookback buffer and total arrays.
__global__ __launch_bounds__(256) void k_hist0(const int* __restrict__ sidx,
                                               const int* __restrict__ ridx,
                                               unsigned short* __restrict__ khm,
                                               unsigned* __restrict__ lb,
                                               unsigned* __restrict__ ktot,
                                               unsigned* __restrict__ vtot,
                                               unsigned* __restrict__ v24tot){
  __shared__ unsigned h[768];
  unsigned t = threadIdx.x, b = blockIdx.x;
  h[t] = 0; h[256+t] = 0; h[512+t] = 0;
  lb[(size_t)b*256u + t] = 0u;
  if (b == 0u){ ktot[t] = 0u; ktot[256+t] = 0u; ktot[512+t] = 0u; }
  else if (b == 1u){ vtot[t] = 0u; vtot[256+t] = 0u; vtot[512+t] = 0u;
                     vtot[768+t] = 0u; v24tot[t] = 0u; }
  __syncthreads();
  size_t base = (size_t)b * TILE;
  #pragma unroll
  for (int r = 0; r < WPT; r++){
    unsigned i = (unsigned)(base + (size_t)r*256 + t);
    unsigned k;
    if (i < S_N)      k = (unsigned)sidx[i];
    else if (i < N1){ int2 rc = ((const int2* __restrict__)ridx)[i - S_N];
                      k = (unsigned)(rc.x * CDIM + rc.y); }
    else              k = PAD_KEY;
    atomicAdd(&h[k & 0xFFu], 1u);
    atomicAdd(&h[256u + ((k >> 8) & 0xFFu)], 1u);
    atomicAdd(&h[512u + ((k >> 16) & 0xFFu)], 1u);
  }
  __syncthreads();
  khm[(size_t)b*768u + t]        = (unsigned short)h[t];
  khm[(size_t)b*768u + 256u + t] = (unsigned short)h[256+t];
  khm[(size_t)b*768u + 512u + t] = (unsigned short)h[512+t];
}

// Column-sum reduce of a dense u16 [NTILES][wcols*256] matrix into u32 totals.
// 16 strips x wcols blocks; 16 atomics per address (low contention, dst
// pre-zeroed by k_hist0).
__global__ __launch_bounds__(256) void k_reduce(const unsigned short* __restrict__ src,
                                                unsigned* __restrict__ dst,
                                                unsigned wcols){
  unsigned t = threadIdx.x;
  unsigned c = blockIdx.x % wcols, strip = blockIdx.x / wcols;
  unsigned width = wcols * 256u, j = c*256u + t;
  const unsigned CH = (NTILES + 15u) / 16u;
  unsigned b0 = strip * CH, b1 = b0 + CH; if (b1 > (unsigned)NTILES) b1 = NTILES;
  unsigned s = 0;
  for (unsigned b = b0; b < b1; b++) s += (unsigned)src[(size_t)b*width + j];
  atomicAdd(&dst[j], s);
}

// Select-phase totals: hist of byte 24 of ~v over candidates A0[0,U).
// Grid-stride over 256 blocks -> only 256 atomics per address.
__global__ __launch_bounds__(256) void k_hist24(const uint64_t* __restrict__ in,
                                                const unsigned* __restrict__ utot,
                                                unsigned* __restrict__ v24tot){
  __shared__ unsigned h[256];
  unsigned t = threadIdx.x;
  unsigned Un = utot[0];
  h[t] = 0; __syncthreads();
  for (unsigned tile = blockIdx.x; tile < (unsigned)NTILES; tile += 256u){
    size_t base = (size_t)tile * TILE;
    if (base >= (size_t)Un) break;
    #pragma unroll
    for (int r = 0; r < WPT; r++){
      unsigned i = (unsigned)(base + (size_t)r*256 + t);
      if (i < Un) atomicAdd(&h[(unsigned)((in[i] >> 24) & 0xFF)], 1u);
    }
  }
  __syncthreads();
  atomicAdd(&v24tot[t], h[t]);
}

// ---- LDS-staged stable radix scatter with decoupled lookback --------------
// Phase A: per-wave stable ranks. Phase B: publish tile digit counts, scan
// global totals in-block, lookback for per-tile prefixes. Phase C: stage in
// LDS by (digit, pos). Phase D: coalesced runs per digit to global.
// MODE 0: plain pass. MODE 3: pass 1, elements recomputed from raw inputs.
// MODE 1: value LSD (synth SENT for i >= Un; write dest < M). MODE 2: final
// output pass. MODE 4: compact with fused cut (M from in-block dtot scan) +
// fused 4-byte kept-element hists (dense u16 out).
template <int MODE>
__device__ __forceinline__ void scatter_body(const uint64_t* __restrict__ in,
                                             uint64_t* __restrict__ out,
                                             float* __restrict__ fout,
                                             unsigned shift,
                                             const unsigned* __restrict__ gtot,
                                             unsigned* __restrict__ lb,
                                             unsigned tag,
                                             const unsigned* __restrict__ nsyn,
                                             const unsigned* __restrict__ mskip,
                                             const int* __restrict__ sidx,
                                             const int* __restrict__ ridx,
                                             const float* __restrict__ rval,
                                             const float* __restrict__ grad,
                                             unsigned* __restrict__ mout,
                                             unsigned short* __restrict__ hm4){
  unsigned t = threadIdx.x, lane = t & 63u, w = t >> 6, b = blockIdx.x;
  unsigned Un = 0u, M = 0u;
  if (MODE == 1 || MODE == 2 || MODE == 4){
    Un = nsyn[0];
    if (MODE != 4) M = mskip[0];
    if ((MODE == 1 || MODE == 2) && b * (unsigned)TILE >= Un){
      // All-sentinel tail tile: publish its counts for successors, no data.
      unsigned cnt = (t == 255u) ? (unsigned)TILE : 0u;
      lb_publish(lb, b, t, cnt, tag);
      lb_walk(lb, b, t, cnt, tag);
      return;
    }
  }
  __shared__ unsigned wrun[4*256];
  __shared__ unsigned gput[256];
  __shared__ unsigned lw[4];
  __shared__ unsigned cutm;
  __shared__ uint64_t stage[TILE];       // 32 KB
  wrun[t] = 0; wrun[256+t] = 0; wrun[512+t] = 0; wrun[768+t] = 0;
  __syncthreads();
  uint64_t ltm = (lane == 0) ? 0ull : (~0ull >> (64u - lane));
  uint64_t elems[WPT]; unsigned rnk[WPT]; unsigned dg[WPT];
  size_t base = (size_t)b * TILE + (size_t)w * (TILE/4);
  #pragma unroll
  for (int r = 0; r < WPT; r++){
    unsigned idx = (unsigned)(base + (size_t)r*64) + lane;
    uint64_t e;
    if (MODE == 3)      e = make_elem(idx, sidx, ridx, rval, grad);
    else if (MODE != 0) e = (idx < Un) ? in[idx] : SENT;
    else                e = in[idx];
    elems[r] = e;
    unsigned d = (unsigned)((e >> shift) & 0xFF);
    uint64_t m = ~0ull;
    #pragma unroll
    for (int bb_ = 0; bb_ < 8; bb_++){
      uint64_t bb = __ballot((d >> bb_) & 1u);
      m &= ((d >> bb_) & 1u) ? bb : ~bb;
    }
    unsigned rr   = (unsigned)__popcll(m & ltm);
    unsigned prev = wrun[w*256 + d];
    __builtin_amdgcn_wave_barrier();
    if (rr == 0) wrun[w*256 + d] = prev + (unsigned)__popcll(m);
    __builtin_amdgcn_wave_barrier();
    rnk[r] = prev + rr;
    dg[r]  = d;
  }
  __syncthreads();
  {
    unsigned d = t;
    unsigned c0 = wrun[d], c1 = wrun[256+d], c2 = wrun[512+d], c3 = wrun[768+d];
    unsigned cnt = c0 + c1 + c2 + c3;
    lb_publish(lb, b, d, cnt, tag);          // unblock successors early
    unsigned tot;
    unsigned ldig  = blockScanExcl(cnt, t, lw, &tot);       // local digit start
    unsigned gt = gtot[d];
    if ((MODE == 1 || MODE == 2 || MODE == 4) && d == 255u)
      gt += (unsigned)NPAD - Un;             // analytic sentinel-tail count
    unsigned tot2;
    unsigned dbase = blockScanExcl(gt, t, lw, &tot2);       // global digit base
    if (MODE == 4){
      unsigned incl = dbase + gt;                            // == k_cut arithmetic
      if (dbase < R_N && incl >= R_N) cutm = incl;
    }
    unsigned excl = lb_walk(lb, b, d, cnt, tag);             // per-tile prefix
    gput[d] = dbase + excl - ldig;
    wrun[d]       = ldig;
    wrun[256 + d] = ldig + c0;
    wrun[512 + d] = ldig + c0 + c1;
    wrun[768 + d] = ldig + c0 + c1 + c2;
  }
  __syncthreads();
  if (MODE == 4){
    M = cutm;
    if (b == 0u && t == 0u) mout[0] = M;     // for later kernels
  }
  #pragma unroll
  for (int r = 0; r < WPT; r++)
    stage[ wrun[w*256 + dg[r]] + rnk[r] ] = elems[r];
  __syncthreads();
  if (MODE == 4){
    // Phase D with fused 4-byte hists of the kept elements.
    __shared__ unsigned vh[1024];
    vh[t] = 0; vh[256+t] = 0; vh[512+t] = 0; vh[768+t] = 0;
    __syncthreads();
    #pragma unroll
    for (int r = 0; r < WPT; r++){
      unsigned j = (unsigned)r * 256u + t;
      uint64_t e = stage[j];
      unsigned d = (unsigned)((e >> shift) & 0xFF);
      unsigned dest = gput[d] + j;
      if (dest < M){
        out[dest] = e;
        atomicAdd(&vh[         (unsigned)( e        & 0xFF)], 1u);
        atomicAdd(&vh[256u  +  (unsigned)((e >> 8)  & 0xFF)], 1u);
        atomicAdd(&vh[512u  +  (unsigned)((e >> 16) & 0xFF)], 1u);
        atomicAdd(&vh[768u  +  (unsigned)((e >> 24) & 0xFF)], 1u);
      }
    }
    __syncthreads();
    hm4[(size_t)b*1024u + t]        = (unsigned short)vh[t];
    hm4[(size_t)b*1024u + 256u + t] = (unsigned short)vh[256+t];
    hm4[(size_t)b*1024u + 512u + t] = (unsigned short)vh[512+t];
    hm4[(size_t)b*1024u + 768u + t] = (unsigned short)vh[768+t];
  } else {
    #pragma unroll
    for (int r = 0; r < WPT; r++){
      unsigned j = (unsigned)r * 256u + t;
      uint64_t e = stage[j];
      unsigned d = (unsigned)((e >> shift) & 0xFF);
      unsigned dest = gput[d] + j;
      if (MODE == 2){
        if (dest < R_N){
          uint32_t key = (uint32_t)(e >> 32);
          fout[2u*dest]        = (float)(key >> 12);
          fout[2u*dest + 1u]   = (float)(key & 4095u);
          fout[2u*R_N + dest]  = __uint_as_float(~(uint32_t)e);
        }
      } else if (MODE == 1){
        if (dest < M) out[dest] = e;
      } else {
        out[dest] = e;
      }
    }
  }
}

__global__ __launch_bounds__(256) void k_scatter(const uint64_t* __restrict__ in,
                                                 uint64_t* __restrict__ out,
                                                 unsigned shift,
                                                 const unsigned* __restrict__ gtot,
                                                 unsigned* __restrict__ lb, unsigned tag){
  scatter_body<0>(in, out, nullptr, shift, gtot, lb, tag, nullptr, nullptr,
                  nullptr, nullptr, nullptr, nullptr, nullptr, nullptr);
}

__global__ __launch_bounds__(256) void k_scatter_b(const int* __restrict__ sidx,
                                                   const int* __restrict__ ridx,
                                                   const float* __restrict__ rval,
                                                   const float* __restrict__ grad,
                                                   uint64_t* __restrict__ out,
                                                   unsigned shift,
                                                   const unsigned* __restrict__ gtot,
                                                   unsigned* __restrict__ lb, unsigned tag){
  scatter_body<3>(nullptr, out, nullptr, shift, gtot, lb, tag, nullptr, nullptr,
                  sidx, ridx, rval, grad, nullptr, nullptr);
}

__global__ __launch_bounds__(256) void k_scatter_m(const uint64_t* __restrict__ in,
                                                   uint64_t* __restrict__ out,
                                                   unsigned shift,
                                                   const unsigned* __restrict__ gtot,
                                                   unsigned* __restrict__ lb, unsigned tag,
                                                   const unsigned* __restrict__ mvar){
  scatter_body<1>(in, out, nullptr, shift, gtot, lb, tag, mvar, mvar,
                  nullptr, nullptr, nullptr, nullptr, nullptr, nullptr);
}

__global__ __launch_bounds__(256) void k_scatter_mc(const uint64_t* __restrict__ in,
                                                    uint64_t* __restrict__ out,
                                                    unsigned shift,
                                                    const unsigned* __restrict__ gtot,
                                                    unsigned* __restrict__ lb, unsigned tag,
                                                    const unsigned* __restrict__ nsyn,
                                                    unsigned* __restrict__ mout,
                                                    unsigned short* __restrict__ hm4){
  scatter_body<4>(in, out, nullptr, shift, gtot, lb, tag, nsyn, nullptr,
                  nullptr, nullptr, nullptr, nullptr, mout, hm4);
}

__global__ __launch_bounds__(256) void k_scatter_out(const uint64_t* __restrict__ in,
                                                     float* __restrict__ fout,
                                                     unsigned shift,
                                                     const unsigned* __restrict__ gtot,
                                                     unsigned* __restrict__ lb, unsigned tag,
                                                     const unsigned* __restrict__ mvar){
  scatter_body<2>(in, nullptr, fout, shift, gtot, lb, tag, mvar, mvar,
                  nullptr, nullptr, nullptr, nullptr, nullptr, nullptr);
}

// Count real segment heads per 256-elem block (phantom pad-head excluded so
// the scanned total is the exact candidate count U).
__global__ __launch_bounds__(256) void k_headcount(const uint64_t* __restrict__ in,
                                                   unsigned* __restrict__ hcnt){
  __shared__ unsigned wc[4];
  unsigned t = threadIdx.x, lane = t & 63u, w = t >> 6;
  size_t p = (size_t)blockIdx.x * 256 + t;
  uint64_t e = in[p];
  uint32_t k = (uint32_t)(e >> 32);
  bool head = ((p == 0) || ((uint32_t)(in[p-1] >> 32) != k)) && ((uint32_t)e != PAD_VAL);
  uint64_t m = __ballot(head);
  if (lane == 0) wc[w] = (unsigned)__popcll(m);
  __syncthreads();
  if (t == 0) hcnt[blockIdx.x] = wc[0] + wc[1] + wc[2] + wc[3];
}

// Fast single-block scan of NSB head counts via u16 LDS staging; writes U.
__global__ __launch_bounds__(256) void k_scanheads(unsigned* __restrict__ hcnt,
                                                   unsigned* __restrict__ utot){
  __shared__ unsigned short buf[NSB];    // counts <= 256 fit u16; 34.4 KB
  __shared__ unsigned lw[4];
  unsigned t = threadIdx.x;
  for (unsigned i = t; i < NSB; i += 256) buf[i] = (unsigned short)hcnt[i];
  __syncthreads();
  const unsigned CH = (NSB + 255) / 256; // 68 elems/thread, blocked
  unsigned s = 0;
  for (unsigned k = 0; k < CH; k++){
    unsigned i = t * CH + k;
    if (i < NSB) s += buf[i];
  }
  unsigned tot;
  unsigned carry = blockScanExcl(s, t, lw, &tot);
  for (unsigned k = 0; k < CH; k++){
    unsigned i = t * CH + k;
    if (i < NSB){ unsigned v = buf[i]; hcnt[i] = carry; carry += v; }
  }
  if (t == 0) utot[0] = tot;
}

// In-order segmented sum: head thread walks its key segment sequentially
// (original contribution order thanks to the stable key sort) -> fp32 sum is
// bit-identical to segment_sum. One thread per ELEMENT (TLP hides walks).
__global__ __launch_bounds__(256) void k_segsum(const uint64_t* __restrict__ in,
                                                uint64_t* __restrict__ out,
                                                const unsigned* __restrict__ hbase){
  __shared__ unsigned wc[4], woffs[4];
  unsigned t = threadIdx.x, lane = t & 63u, w = t >> 6;
  size_t p = (size_t)blockIdx.x * 256 + t;
  uint64_t e0 = in[p];
  uint32_t k = (uint32_t)(e0 >> 32);
  bool head = ((p == 0) || ((uint32_t)(in[p-1] >> 32) != k)) && ((uint32_t)e0 != PAD_VAL);
  uint64_t m = __ballot(head);
  if (lane == 0) wc[w] = (unsigned)__popcll(m);
  __syncthreads();
  if (t == 0){ unsigned a = 0; for (int i = 0; i < 4; i++){ woffs[i] = a; a += wc[i]; } }
  __syncthreads();
  if (head){
    uint64_t ltm = (lane == 0) ? 0ull : (~0ull >> (64u - lane));
    unsigned rank = (unsigned)__popcll(m & ltm);
    unsigned oidx = hbase[blockIdx.x] + woffs[w] + rank;
    float s = __uint_as_float((uint32_t)e0);
    size_t q = p + 1;
    while (q < NPAD){
      uint64_t e = in[q];
      if ((uint32_t)(e >> 32) != k) break;
      uint32_t vb = (uint32_t)e;
      if (vb == PAD_VAL) break;
      s += __uint_as_float(vb);
      q++;
    }
    out[oidx] = ((uint64_t)k << 32) | (uint64_t)(uint32_t)(~__float_as_uint(s));
  }
}

extern "C" void kernel_launch(void* const* d_in, const int* in_sizes, int n_in,
                              void* d_out, int out_size, void* d_ws, size_t ws_size,
                              hipStream_t stream) {
  const int*   sidx = (const int*)d_in[0];
  const int*   ridx = (const int*)d_in[1];
  const float* rval = (const float*)d_in[2];
  const float* grad = (const float*)d_in[3];
  float* out = (float*)d_out;

  uint64_t* A0   = (uint64_t*)d_ws;                        // 35.3 MB
  uint64_t* A1   = A0 + NPAD;                              // 35.3 MB
  unsigned short* hmx = (unsigned short*)(A1 + NPAD);      // 2.2 MB (khm/hm4/hcnt overlay)
  unsigned* lb   = (unsigned*)(hmx + (size_t)NTILES*1024); // 1.1 MB lookback
  unsigned* ktot = lb + (size_t)NTILES*256;                // 3 KB
  unsigned* vtot = ktot + 768;                             // 4 KB
  unsigned* v24t = vtot + 1024;                            // 1 KB
  unsigned* utot = v24t + 256;                             // 4 B
  unsigned* mvar = utot + 1;                               // 4 B
  unsigned* hcnt = mvar + 1;                               // 67 KB

  // Upfront hists of all 3 key bytes + zero lb/totals.
  k_hist0 <<<NTILES, 256, 0, stream>>>(sidx, ridx, hmx, lb, ktot, vtot, v24t);
  k_reduce<<<16*3,   256, 0, stream>>>(hmx, ktot, 3);

  // Stable key sort: 3 x 8-bit lookback passes. Pass 1 recomputes elements
  // from the raw inputs. inputs->A1->A0->A1.
  k_scatter_b<<<NTILES, 256, 0, stream>>>(sidx, ridx, rval, grad, A1, 32, ktot,       lb, 1);
  k_scatter  <<<NTILES, 256, 0, stream>>>(A1, A0, 40, ktot + 256, lb, 2);
  k_scatter  <<<NTILES, 256, 0, stream>>>(A0, A1, 48, ktot + 512, lb, 3);

  // Coalesce. Candidates written dense & key-ascending into A0[0, U).
  k_headcount<<<NSB, 256, 0, stream>>>(A1, hcnt);
  k_scanheads<<<1,   256, 0, stream>>>(hcnt, utot);
  k_segsum   <<<NSB, 256, 0, stream>>>(A1, A0, hcnt);

  // Select: byte-24 totals, then lookback-compact with fused cut (M in-kernel)
  // and fused 4-byte kept-element hists.
  k_hist24    <<<256,    256, 0, stream>>>(A0, utot, v24t);
  k_scatter_mc<<<NTILES, 256, 0, stream>>>(A0, A1, 24, v24t, lb, 4, utot, mvar, hmx);
  k_reduce    <<<16*4,   256, 0, stream>>>(hmx, vtot, 4);

  // Stable value sort over only M elements: 4 x 8-bit lookback LSD passes,
  // final pass fused with output emission. A1->A0->A1->A0->out.
  k_scatter_m  <<<NTILES, 256, 0, stream>>>(A1, A0, 0,  vtot,       lb, 5, mvar);
  k_scatter_m  <<<NTILES, 256, 0, stream>>>(A0, A1, 8,  vtot + 256, lb, 6, mvar);
  k_scatter_m  <<<NTILES, 256, 0, stream>>>(A1, A0, 16, vtot + 512, lb, 7, mvar);
  k_scatter_out<<<NTILES, 256, 0, stream>>>(A0, out, 24, vtot + 768, lb, 8, mvar);
}

// Round 8
// 1605.020 us; speedup vs baseline: 6.8148x; 6.8148x over previous
//
#include <hip/hip_runtime.h>
#include <stdint.h>

#define CDIM   4096
#define S_N    3355443
#define R_N    1048576
#define N1     (S_N + R_N)                 // 4404019 contributions
#define TILE   4096
#define WPT    (TILE / 256)                // 16 elements per thread
#define NTILES ((N1 + TILE - 1) / TILE)    // 1076
#define NPAD   (NTILES * TILE)             // 4407296
#define NSB    (NPAD / 256)                // 17216 (== NTILES*16)
#define SR_CH  ((NTILES + 255) / 256)      // 5 row entries per thread in scanrows
#define PAD_KEY 0xFFFFFFu
#define PAD_VAL 0xFFFFFFFFu                // impossible value bits (sums are >= +0)
#define SENT  (((uint64_t)PAD_KEY << 32) | (uint64_t)PAD_VAL)
#define ADJF  ((float)(1.0 - (3355443.0 / 16777216.0) * (1.0 - 0.95)))

// Exclusive block-wide scan over 256 threads (4 waves). Contains syncthreads.
static __device__ __forceinline__ unsigned blockScanExcl(unsigned v, unsigned t,
                                                         unsigned* lw, unsigned* tot){
  unsigned lane = t & 63u, w = t >> 6;
  unsigned x = v;
  #pragma unroll
  for (int off = 1; off < 64; off <<= 1){
    unsigned y = __shfl_up(x, off, 64);
    if (lane >= (unsigned)off) x += y;
  }
  if (lane == 63u) lw[w] = x;
  __syncthreads();
  unsigned woff = 0;
  for (unsigned i = 0; i < w; i++) woff += lw[i];
  *tot = lw[0] + lw[1] + lw[2] + lw[3];
  __syncthreads();
  return x + woff - v;
}

// Recompute element i of the contribution array from the raw inputs.
// Samples first, then decayed buffer entries, then padding -> stable sort
// preserves segment_sum's accumulation order exactly.
static __device__ __forceinline__ uint64_t make_elem(unsigned i,
                                                     const int* __restrict__ sidx,
                                                     const int* __restrict__ ridx,
                                                     const float* __restrict__ rval,
                                                     const float* __restrict__ grad){
  uint32_t key, vb;
  if (i < S_N){
    key = (uint32_t)sidx[i];
    vb  = __float_as_uint(fabsf(grad[i]));
  } else if (i < N1){
    unsigned j = i - S_N;
    int2 rc = ((const int2* __restrict__)ridx)[j];
    key = (uint32_t)(rc.x * CDIM + rc.y);
    vb = __float_as_uint(ADJF * rval[j]);
  } else {
    key = PAD_KEY; vb = PAD_VAL;
  }
  return ((uint64_t)key << 32) | (uint64_t)vb;
}

// Pass-1 key histogram straight from the inputs (key low byte only: needs
// sidx + ridx.y, NOT grad/rval, and writes no element array). Also zeroes the
// coalesce lookback buffer (workspace is re-poisoned every run: mandatory).
__global__ __launch_bounds__(256) void k_hist0(const int* __restrict__ sidx,
                                               const int* __restrict__ ridx,
                                               unsigned* __restrict__ gh,
                                               unsigned* __restrict__ lb){
  __shared__ unsigned h[256];
  unsigned t = threadIdx.x, b = blockIdx.x;
  h[t] = 0;
  if (t < 16u) lb[b * 16u + t] = 0u;     // NSB == NTILES*16 exactly
  __syncthreads();
  size_t base = (size_t)b * TILE;
  #pragma unroll
  for (int r = 0; r < WPT; r++){
    unsigned i = (unsigned)(base + (size_t)r*256 + t);
    unsigned kb;
    if (i < S_N)       kb = ((uint32_t)sidx[i]) & 0xFFu;
    else if (i < N1)   kb = ((uint32_t)ridx[2u*(i - S_N) + 1u]) & 0xFFu; // col low byte
    else               kb = 0xFFu;                                       // PAD_KEY & 0xFF
    atomicAdd(&h[kb], 1u);         // LDS atomic only
  }
  __syncthreads();
  gh[t * NTILES + b] = h[t];
}

// Per-tile 256-bin histogram of digit (e >> shift) & 0xFF. Layout [digit][tile].
__global__ __launch_bounds__(256) void k_hist(const uint64_t* __restrict__ in, unsigned shift,
                                              unsigned* __restrict__ gh){
  __shared__ unsigned h[256];
  unsigned t = threadIdx.x;
  h[t] = 0; __syncthreads();
  size_t base = (size_t)blockIdx.x * TILE;
  #pragma unroll
  for (int r = 0; r < WPT; r++){
    uint64_t e = in[base + (size_t)r*256 + t];
    atomicAdd(&h[(unsigned)((e >> shift) & 0xFF)], 1u);
  }
  __syncthreads();
  gh[t * NTILES + blockIdx.x] = h[t];
}

// Histogram with sentinel synthesis for i >= nsyn[0]: elements beyond the
// live prefix are counted as digit 255 without touching memory. Tail tiles
// write their (constant) column and return.
__global__ __launch_bounds__(256) void k_hist_syn(const uint64_t* __restrict__ in, unsigned shift,
                                                  unsigned* __restrict__ gh,
                                                  const unsigned* __restrict__ nsyn){
  __shared__ unsigned h[256];
  unsigned t = threadIdx.x;
  unsigned Un = nsyn[0];
  size_t base = (size_t)blockIdx.x * TILE;
  if (base >= (size_t)Un){
    gh[t * NTILES + blockIdx.x] = (t == 255u) ? (unsigned)TILE : 0u;
    return;
  }
  h[t] = 0; __syncthreads();
  #pragma unroll
  for (int r = 0; r < WPT; r++){
    unsigned i = (unsigned)(base + (size_t)r*256 + t);
    uint64_t e = (i < Un) ? in[i] : SENT;
    atomicAdd(&h[(unsigned)((e >> shift) & 0xFF)], 1u);
  }
  __syncthreads();
  gh[t * NTILES + blockIdx.x] = h[t];
}

// Row scan: block d turns gh[d][*] into exclusive tile prefixes + digit total.
// Blocked per-thread ownership + ONE blockScan (2 syncthreads instead of 10).
__global__ __launch_bounds__(256) void k_scanrows(unsigned* __restrict__ gh,
                                                  unsigned* __restrict__ dtot){
  __shared__ unsigned lw[4];
  unsigned d = blockIdx.x, t = threadIdx.x;
  unsigned rowbase = d * NTILES;
  unsigned vals[SR_CH];
  unsigned s = 0;
  #pragma unroll
  for (int k = 0; k < SR_CH; k++){
    unsigned i = t * SR_CH + (unsigned)k;
    vals[k] = (i < NTILES) ? gh[rowbase + i] : 0u;
    s += vals[k];
  }
  unsigned tot;
  unsigned carry = blockScanExcl(s, t, lw, &tot);
  #pragma unroll
  for (int k = 0; k < SR_CH; k++){
    unsigned i = t * SR_CH + (unsigned)k;
    if (i < NTILES){ gh[rowbase + i] = carry; carry += vals[k]; }
  }
  if (t == 0) dtot[d] = tot;
}

// ---- LDS-staged stable radix scatter -------------------------------------
// Phase A: per-wave stable ranks. Phase B: block digit scan -> bases.
// Phase C: stage tile in LDS ordered by (digit, pos). Phase D: coalesced
// runs per digit to global.
// MODE 0: plain pass over the full NPAD array.
// MODE 1: M-mode (value LSD): synthesize SENT for i >= nsyn[0]; write only
//         dest < mskip[0].
// MODE 2: M-mode final: emit output rows for dest < R_N.
// MODE 3: build-recompute: elements recomputed from raw inputs (key pass 1).
// MODE 4: compact with FUSED CUT: M computed in phase B from the dtot scan
//         (identical arithmetic to a standalone k_cut); block 0 persists mvar.
template <int MODE>
__device__ __forceinline__ void scatter_body(const uint64_t* __restrict__ in,
                                             uint64_t* __restrict__ out,
                                             float* __restrict__ fout,
                                             unsigned shift,
                                             const unsigned* __restrict__ gh,
                                             const unsigned* __restrict__ dtot,
                                             const unsigned* __restrict__ nsyn,
                                             const unsigned* __restrict__ mskip,
                                             const int* __restrict__ sidx,
                                             const int* __restrict__ ridx,
                                             const float* __restrict__ rval,
                                             const float* __restrict__ grad,
                                             unsigned* __restrict__ mout){
  unsigned Un = 0u, M = 0u;
  if (MODE == 1 || MODE == 2 || MODE == 4){
    Un = nsyn[0];
    if (MODE != 4){
      M = mskip[0];
      if ((unsigned)blockIdx.x * TILE >= Un && M <= Un) return;
    }
  }
  __shared__ unsigned wrun[4*256];
  __shared__ unsigned gput[256];
  __shared__ unsigned lw[4];
  __shared__ unsigned cutm;
  __shared__ uint64_t stage[TILE];       // 32 KB
  unsigned t = threadIdx.x, lane = t & 63u, w = t >> 6;
  wrun[t] = 0; wrun[256+t] = 0; wrun[512+t] = 0; wrun[768+t] = 0;
  __syncthreads();
  uint64_t ltm = (lane == 0) ? 0ull : (~0ull >> (64u - lane));
  uint64_t elems[WPT]; unsigned rnk[WPT]; unsigned dg[WPT];
  size_t base = (size_t)blockIdx.x * TILE + (size_t)w * (TILE/4);
  #pragma unroll
  for (int r = 0; r < WPT; r++){
    unsigned idx = (unsigned)(base + (size_t)r*64) + lane;
    uint64_t e;
    if (MODE == 3)      e = make_elem(idx, sidx, ridx, rval, grad);
    else if (MODE != 0) e = (idx < Un) ? in[idx] : SENT;
    else                e = in[idx];
    elems[r] = e;
    unsigned d = (unsigned)((e >> shift) & 0xFF);
    uint64_t m = ~0ull;
    #pragma unroll
    for (int b = 0; b < 8; b++){
      uint64_t bb = __ballot((d >> b) & 1u);
      m &= ((d >> b) & 1u) ? bb : ~bb;
    }
    unsigned rr   = (unsigned)__popcll(m & ltm);
    unsigned prev = wrun[w*256 + d];
    __builtin_amdgcn_wave_barrier();
    if (rr == 0) wrun[w*256 + d] = prev + (unsigned)__popcll(m);
    __builtin_amdgcn_wave_barrier();
    rnk[r] = prev + rr;
    dg[r]  = d;
  }
  __syncthreads();
  {
    unsigned d = t;
    unsigned c0 = wrun[d], c1 = wrun[256+d], c2 = wrun[512+d], c3 = wrun[768+d];
    unsigned cnt = c0 + c1 + c2 + c3;
    unsigned tot;
    unsigned ldig  = blockScanExcl(cnt, t, lw, &tot);       // local digit start
    unsigned tot2;
    unsigned dbase = blockScanExcl(dtot[d], t, lw, &tot2);  // global digit base
    if (MODE == 4){
      unsigned incl = dbase + dtot[d];                      // == k_cut arithmetic
      if (dbase < R_N && incl >= R_N) cutm = incl;
    }
    gput[d] = dbase + gh[d * NTILES + blockIdx.x] - ldig;
    wrun[d]       = ldig;
    wrun[256 + d] = ldig + c0;
    wrun[512 + d] = ldig + c0 + c1;
    wrun[768 + d] = ldig + c0 + c1 + c2;
  }
  __syncthreads();
  if (MODE == 4){
    M = cutm;
    if (blockIdx.x == 0u && t == 0u) mout[0] = M;           // for later kernels
  }
  #pragma unroll
  for (int r = 0; r < WPT; r++)
    stage[ wrun[w*256 + dg[r]] + rnk[r] ] = elems[r];
  __syncthreads();
  #pragma unroll
  for (int r = 0; r < WPT; r++){
    unsigned j = (unsigned)r * 256u + t;
    uint64_t e = stage[j];
    unsigned d = (unsigned)((e >> shift) & 0xFF);
    unsigned dest = gput[d] + j;
    if (MODE == 2){
      if (dest < R_N){
        uint32_t key = (uint32_t)(e >> 32);
        fout[2u*dest]        = (float)(key >> 12);
        fout[2u*dest + 1u]   = (float)(key & 4095u);
        fout[2u*R_N + dest]  = __uint_as_float(~(uint32_t)e);
      }
    } else if (MODE == 1 || MODE == 4){
      if (dest < M) out[dest] = e;
    } else {
      out[dest] = e;
    }
  }
}

__global__ __launch_bounds__(256) void k_scatter(const uint64_t* __restrict__ in,
                                                 uint64_t* __restrict__ out,
                                                 unsigned shift,
                                                 const unsigned* __restrict__ gh,
                                                 const unsigned* __restrict__ dtot){
  scatter_body<0>(in, out, nullptr, shift, gh, dtot, nullptr, nullptr,
                  nullptr, nullptr, nullptr, nullptr, nullptr);
}

__global__ __launch_bounds__(256) void k_scatter_b(const int* __restrict__ sidx,
                                                   const int* __restrict__ ridx,
                                                   const float* __restrict__ rval,
                                                   const float* __restrict__ grad,
                                                   uint64_t* __restrict__ out,
                                                   unsigned shift,
                                                   const unsigned* __restrict__ gh,
                                                   const unsigned* __restrict__ dtot){
  scatter_body<3>(nullptr, out, nullptr, shift, gh, dtot, nullptr, nullptr,
                  sidx, ridx, rval, grad, nullptr);
}

__global__ __launch_bounds__(256) void k_scatter_m(const uint64_t* __restrict__ in,
                                                   uint64_t* __restrict__ out,
                                                   unsigned shift,
                                                   const unsigned* __restrict__ gh,
                                                   const unsigned* __restrict__ dtot,
                                                   const unsigned* __restrict__ nsyn,
                                                   const unsigned* __restrict__ mskip){
  scatter_body<1>(in, out, nullptr, shift, gh, dtot, nsyn, mskip,
                  nullptr, nullptr, nullptr, nullptr, nullptr);
}

__global__ __launch_bounds__(256) void k_scatter_mc(const uint64_t* __restrict__ in,
                                                    uint64_t* __restrict__ out,
                                                    unsigned shift,
                                                    const unsigned* __restrict__ gh,
                                                    const unsigned* __restrict__ dtot,
                                                    const unsigned* __restrict__ nsyn,
                                                    unsigned* __restrict__ mout){
  scatter_body<4>(in, out, nullptr, shift, gh, dtot, nsyn, nullptr,
                  nullptr, nullptr, nullptr, nullptr, mout);
}

__global__ __launch_bounds__(256) void k_scatter_out(const uint64_t* __restrict__ in,
                                                     float* __restrict__ fout,
                                                     unsigned shift,
                                                     const unsigned* __restrict__ gh,
                                                     const unsigned* __restrict__ dtot,
                                                     const unsigned* __restrict__ nsyn){
  scatter_body<2>(in, nullptr, fout, shift, gh, dtot, nsyn, nsyn,
                  nullptr, nullptr, nullptr, nullptr, nullptr);
}

// Fused coalesce: headcount + block-base prefix + in-order segmented sum in
// ONE pass, preserving ONE THREAD PER ELEMENT (the r5 fusion failed because
// it packed 16 elems/thread and serialized the latency-bound walks; this
// keeps the proven segsum shape). The block's output base comes from the
// r5-validated SINGLE-WORD 64-wide windowed decoupled lookback (aggregate
// published immediately; NOT the r7 per-digit form). lb zeroed by k_hist0.
// lb word: [31:30] status (0=unpub, 1=aggregate, 2=inclusive), [29:0] count.
__global__ __launch_bounds__(256) void k_coalesce(const uint64_t* __restrict__ in,
                                                  uint64_t* __restrict__ out,
                                                  unsigned* __restrict__ lb,
                                                  unsigned* __restrict__ utot){
  __shared__ unsigned wc[4], woffs[4];
  __shared__ unsigned hb;
  unsigned b = blockIdx.x, t = threadIdx.x, lane = t & 63u, w = t >> 6;
  size_t p = (size_t)b * 256 + t;
  uint64_t e0 = in[p];
  uint32_t k = (uint32_t)(e0 >> 32);
  bool head = ((p == 0) || ((uint32_t)(in[p-1] >> 32) != k)) && ((uint32_t)e0 != PAD_VAL);
  uint64_t m = __ballot(head);
  if (lane == 0) wc[w] = (unsigned)__popcll(m);
  __syncthreads();
  if (t == 0){ unsigned a = 0; for (int i = 0; i < 4; i++){ woffs[i] = a; a += wc[i]; } }
  if (w == 0u){
    unsigned cnt = wc[0] + wc[1] + wc[2] + wc[3];
    if (lane == 0u)
      __hip_atomic_store(&lb[b], ((b == 0u) ? (2u<<30) : (1u<<30)) | cnt,
                         __ATOMIC_RELEASE, __HIP_MEMORY_SCOPE_AGENT);
    unsigned run = 0u;
    if (b > 0u){
      int p0 = (int)b - 1;
      for (;;){
        int idx = p0 - (int)lane;
        unsigned v2 = (idx >= 0)
          ? __hip_atomic_load(&lb[idx], __ATOMIC_ACQUIRE, __HIP_MEMORY_SCOPE_AGENT)
          : (2u << 30);
        if (__ballot((v2 >> 30) == 0u)){ __builtin_amdgcn_s_sleep(1); continue; }
        unsigned long long im = __ballot((v2 >> 30) == 2u);
        unsigned cv = v2 & 0x3FFFFFFFu;
        bool fin = (im != 0ull);
        unsigned contrib;
        if (fin){
          unsigned li = (unsigned)__ffsll((long long)im) - 1u;  // nearest inclusive
          contrib = (lane <= li) ? cv : 0u;
        } else {
          contrib = cv;
        }
        #pragma unroll
        for (int off = 1; off < 64; off <<= 1)
          contrib += (unsigned)__shfl_xor((int)contrib, off, 64);
        run += contrib;
        if (fin) break;
        p0 -= 64;
      }
      if (lane == 0u)
        __hip_atomic_store(&lb[b], (2u<<30) | (run + cnt),
                           __ATOMIC_RELEASE, __HIP_MEMORY_SCOPE_AGENT);
    }
    if (lane == 0u){
      hb = run;
      if (b == (unsigned)(NSB - 1)) utot[0] = run + cnt;
    }
  }
  __syncthreads();
  if (head){
    uint64_t ltm = (lane == 0) ? 0ull : (~0ull >> (64u - lane));
    unsigned rank = (unsigned)__popcll(m & ltm);
    unsigned oidx = hb + woffs[w] + rank;
    float s = __uint_as_float((uint32_t)e0);
    size_t q = p + 1;
    while (q < NPAD){
      uint64_t e = in[q];
      if ((uint32_t)(e >> 32) != k) break;
      uint32_t vb = (uint32_t)e;
      if (vb == PAD_VAL) break;
      s += __uint_as_float(vb);
      q++;
    }
    out[oidx] = ((uint64_t)k << 32) | (uint64_t)(uint32_t)(~__float_as_uint(s));
  }
}

extern "C" void kernel_launch(void* const* d_in, const int* in_sizes, int n_in,
                              void* d_out, int out_size, void* d_ws, size_t ws_size,
                              hipStream_t stream) {
  const int*   sidx = (const int*)d_in[0];
  const int*   ridx = (const int*)d_in[1];
  const float* rval = (const float*)d_in[2];
  const float* grad = (const float*)d_in[3];
  float* out = (float*)d_out;

  uint64_t* A0   = (uint64_t*)d_ws;                       // 35.3 MB
  uint64_t* A1   = A0 + NPAD;                             // 35.3 MB
  unsigned* gh   = (unsigned*)(A1 + NPAD);                // 1.1 MB
  unsigned* dtot = gh + 256 * NTILES;                     // 1 KB
  unsigned* lb   = dtot + 256;                            // 67 KB (lookback)
  unsigned* utot = lb + NSB;                              // 4 B
  unsigned* mvar = utot + 1;                              // 4 B

  // Stable key sort: 24 bits, 3 x 8-bit passes. Pass 1 recomputes elements
  // from the raw inputs (no element-array build/read). inputs->A1->A0->A1.
  // k_hist0 also zeroes the coalesce lookback buffer.
  k_hist0    <<<NTILES, 256, 0, stream>>>(sidx, ridx, gh, lb);
  k_scanrows <<<256,    256, 0, stream>>>(gh, dtot);
  k_scatter_b<<<NTILES, 256, 0, stream>>>(sidx, ridx, rval, grad, A1, 32, gh, dtot);
  k_hist     <<<NTILES, 256, 0, stream>>>(A1, 40, gh);
  k_scanrows <<<256,    256, 0, stream>>>(gh, dtot);
  k_scatter  <<<NTILES, 256, 0, stream>>>(A1, A0, 40, gh, dtot);
  k_hist     <<<NTILES, 256, 0, stream>>>(A0, 48, gh);
  k_scanrows <<<256,    256, 0, stream>>>(gh, dtot);
  k_scatter  <<<NTILES, 256, 0, stream>>>(A0, A1, 48, gh, dtot);

  // Fused coalesce (1 elem/thread; single-word windowed lookback). Candidates
  // written dense & key-ascending into A0[0, U); writes U.
  k_coalesce<<<NSB, 256, 0, stream>>>(A1, A0, lb, utot);

  // Select: histogram high byte of ~v; compact scatter computes the cut M
  // in-kernel from the dtot scan (fused k_cut) and persists mvar.
  k_hist_syn  <<<NTILES, 256, 0, stream>>>(A0, 24, gh, utot);
  k_scanrows  <<<256,    256, 0, stream>>>(gh, dtot);
  k_scatter_mc<<<NTILES, 256, 0, stream>>>(A0, A1, 24, gh, dtot, utot, mvar);

  // Stable value sort over only M elements: 4 x 8-bit LSD passes,
  // final pass fused with output emission. A1->A0->A1->A0->out.
  k_hist_syn <<<NTILES, 256, 0, stream>>>(A1, 0, gh, mvar);
  k_scanrows <<<256,    256, 0, stream>>>(gh, dtot);
  k_scatter_m<<<NTILES, 256, 0, stream>>>(A1, A0, 0, gh, dtot, mvar, mvar);
  k_hist_syn <<<NTILES, 256, 0, stream>>>(A0, 8, gh, mvar);
  k_scanrows <<<256,    256, 0, stream>>>(gh, dtot);
  k_scatter_m<<<NTILES, 256, 0, stream>>>(A0, A1, 8, gh, dtot, mvar, mvar);
  k_hist_syn <<<NTILES, 256, 0, stream>>>(A1, 16, gh, mvar);
  k_scanrows <<<256,    256, 0, stream>>>(gh, dtot);
  k_scatter_m<<<NTILES, 256, 0, stream>>>(A1, A0, 16, gh, dtot, mvar, mvar);
  k_hist_syn   <<<NTILES, 256, 0, stream>>>(A0, 24, gh, mvar);
  k_scanrows   <<<256,    256, 0, stream>>>(gh, dtot);
  k_scatter_out<<<NTILES, 256, 0, stream>>>(A0, out, 24, gh, dtot, mvar);
}

// Round 9
// 394.967 us; speedup vs baseline: 27.6933x; 4.0637x over previous
//
#include <hip/hip_runtime.h>
#include <stdint.h>

#define CDIM   4096
#define S_N    3355443
#define R_N    1048576
#define N1     (S_N + R_N)                 // 4404019 contributions
#define TILE   4096
#define WPT    (TILE / 256)                // 16 elements per thread
#define NTILES ((N1 + TILE - 1) / TILE)    // 1076
#define NPAD   (NTILES * TILE)             // 4407296
#define NSB    (NPAD / 256)                // 17216 (== NTILES*16)
#define SR_CH  ((NTILES + 255) / 256)      // 5 row entries per thread in scanrows
#define PAD_KEY 0xFFFFFFu
#define PAD_VAL 0xFFFFFFFFu                // impossible value bits (sums are >= +0)
#define SENT  (((uint64_t)PAD_KEY << 32) | (uint64_t)PAD_VAL)
#define ADJF  ((float)(1.0 - (3355443.0 / 16777216.0) * (1.0 - 0.95)))

// Exclusive block-wide scan over 256 threads (4 waves). Contains syncthreads.
static __device__ __forceinline__ unsigned blockScanExcl(unsigned v, unsigned t,
                                                         unsigned* lw, unsigned* tot){
  unsigned lane = t & 63u, w = t >> 6;
  unsigned x = v;
  #pragma unroll
  for (int off = 1; off < 64; off <<= 1){
    unsigned y = __shfl_up(x, off, 64);
    if (lane >= (unsigned)off) x += y;
  }
  if (lane == 63u) lw[w] = x;
  __syncthreads();
  unsigned woff = 0;
  for (unsigned i = 0; i < w; i++) woff += lw[i];
  *tot = lw[0] + lw[1] + lw[2] + lw[3];
  __syncthreads();
  return x + woff - v;
}

// Recompute element i of the contribution array from the raw inputs.
// Samples first, then decayed buffer entries, then padding -> stable sort
// preserves segment_sum's accumulation order exactly.
static __device__ __forceinline__ uint64_t make_elem(unsigned i,
                                                     const int* __restrict__ sidx,
                                                     const int* __restrict__ ridx,
                                                     const float* __restrict__ rval,
                                                     const float* __restrict__ grad){
  uint32_t key, vb;
  if (i < S_N){
    key = (uint32_t)sidx[i];
    vb  = __float_as_uint(fabsf(grad[i]));
  } else if (i < N1){
    unsigned j = i - S_N;
    int2 rc = ((const int2* __restrict__)ridx)[j];
    key = (uint32_t)(rc.x * CDIM + rc.y);
    vb = __float_as_uint(ADJF * rval[j]);
  } else {
    key = PAD_KEY; vb = PAD_VAL;
  }
  return ((uint64_t)key << 32) | (uint64_t)vb;
}

// Pass-1 key histogram straight from the inputs (key low byte only: needs
// sidx + ridx.y, NOT grad/rval, and writes no element array).
__global__ __launch_bounds__(256) void k_hist0(const int* __restrict__ sidx,
                                               const int* __restrict__ ridx,
                                               unsigned* __restrict__ gh){
  __shared__ unsigned h[256];
  unsigned t = threadIdx.x, b = blockIdx.x;
  h[t] = 0; __syncthreads();
  size_t base = (size_t)b * TILE;
  #pragma unroll
  for (int r = 0; r < WPT; r++){
    unsigned i = (unsigned)(base + (size_t)r*256 + t);
    unsigned kb;
    if (i < S_N)       kb = ((uint32_t)sidx[i]) & 0xFFu;
    else if (i < N1)   kb = ((uint32_t)ridx[2u*(i - S_N) + 1u]) & 0xFFu; // col low byte
    else               kb = 0xFFu;                                       // PAD_KEY & 0xFF
    atomicAdd(&h[kb], 1u);         // LDS atomic only
  }
  __syncthreads();
  gh[t * NTILES + b] = h[t];
}

// Per-tile 256-bin histogram of digit (e >> shift) & 0xFF. Layout [digit][tile].
__global__ __launch_bounds__(256) void k_hist(const uint64_t* __restrict__ in, unsigned shift,
                                              unsigned* __restrict__ gh){
  __shared__ unsigned h[256];
  unsigned t = threadIdx.x;
  h[t] = 0; __syncthreads();
  size_t base = (size_t)blockIdx.x * TILE;
  #pragma unroll
  for (int r = 0; r < WPT; r++){
    uint64_t e = in[base + (size_t)r*256 + t];
    atomicAdd(&h[(unsigned)((e >> shift) & 0xFF)], 1u);
  }
  __syncthreads();
  gh[t * NTILES + blockIdx.x] = h[t];
}

// Histogram over the DENSE prefix [0, nsyn[0]) with sentinel synthesis beyond
// it. Tail tiles write their (constant) column and return.
__global__ __launch_bounds__(256) void k_hist_syn(const uint64_t* __restrict__ in, unsigned shift,
                                                  unsigned* __restrict__ gh,
                                                  const unsigned* __restrict__ nsyn){
  __shared__ unsigned h[256];
  unsigned t = threadIdx.x;
  unsigned Un = nsyn[0];
  size_t base = (size_t)blockIdx.x * TILE;
  if (base >= (size_t)Un){
    gh[t * NTILES + blockIdx.x] = (t == 255u) ? (unsigned)TILE : 0u;
    return;
  }
  h[t] = 0; __syncthreads();
  #pragma unroll
  for (int r = 0; r < WPT; r++){
    unsigned i = (unsigned)(base + (size_t)r*256 + t);
    uint64_t e = (i < Un) ? in[i] : SENT;
    atomicAdd(&h[(unsigned)((e >> shift) & 0xFF)], 1u);
  }
  __syncthreads();
  gh[t * NTILES + blockIdx.x] = h[t];
}

// Histogram over the GAPPED candidate layout: sub-block sb (256 slots) holds
// hcnt[sb] valid elements as a prefix; the rest are synthesized sentinels.
__global__ __launch_bounds__(256) void k_hist_syn2(const uint64_t* __restrict__ in, unsigned shift,
                                                   unsigned* __restrict__ gh,
                                                   const unsigned* __restrict__ hcnt){
  __shared__ unsigned h[256];
  unsigned t = threadIdx.x, b = blockIdx.x;
  h[t] = 0; __syncthreads();
  size_t base = (size_t)b * TILE;
  #pragma unroll
  for (int r = 0; r < WPT; r++){
    unsigned cnt = hcnt[b * 16u + (unsigned)r];
    uint64_t e = (t < cnt) ? in[base + (size_t)r*256 + t] : SENT;
    atomicAdd(&h[(unsigned)((e >> shift) & 0xFF)], 1u);
  }
  __syncthreads();
  gh[t * NTILES + b] = h[t];
}

// Row scan: block d turns gh[d][*] into exclusive tile prefixes + digit total.
// Blocked per-thread ownership + ONE blockScan (2 syncthreads instead of 10).
__global__ __launch_bounds__(256) void k_scanrows(unsigned* __restrict__ gh,
                                                  unsigned* __restrict__ dtot){
  __shared__ unsigned lw[4];
  unsigned d = blockIdx.x, t = threadIdx.x;
  unsigned rowbase = d * NTILES;
  unsigned vals[SR_CH];
  unsigned s = 0;
  #pragma unroll
  for (int k = 0; k < SR_CH; k++){
    unsigned i = t * SR_CH + (unsigned)k;
    vals[k] = (i < NTILES) ? gh[rowbase + i] : 0u;
    s += vals[k];
  }
  unsigned tot;
  unsigned carry = blockScanExcl(s, t, lw, &tot);
  #pragma unroll
  for (int k = 0; k < SR_CH; k++){
    unsigned i = t * SR_CH + (unsigned)k;
    if (i < NTILES){ gh[rowbase + i] = carry; carry += vals[k]; }
  }
  if (t == 0) dtot[d] = tot;
}

// ---- LDS-staged stable radix scatter -------------------------------------
// Phase A: per-wave stable ranks. Phase B: block digit scan -> bases.
// Phase C: stage tile in LDS ordered by (digit, pos). Phase D: coalesced
// runs per digit to global.
// MODE 0: plain pass over the full NPAD array.
// MODE 1: M-mode (value LSD over dense [0,M)): synthesize SENT for
//         i >= nsyn[0]; write only dest < mskip[0].
// MODE 2: M-mode final: emit output rows for dest < R_N.
// MODE 3: build-recompute: elements recomputed from raw inputs (key pass 1).
// MODE 4: GAPPED compact with FUSED CUT: element validity from hcnt[sb]
//         (prefix of each 256-slot sub-block); M computed in phase B from the
//         dtot scan (identical arithmetic to a standalone k_cut); block 0
//         persists mvar. Sentinels land in bin 255 which is always >= M, so
//         none is ever written and kept-element placement is unchanged.
template <int MODE>
__device__ __forceinline__ void scatter_body(const uint64_t* __restrict__ in,
                                             uint64_t* __restrict__ out,
                                             float* __restrict__ fout,
                                             unsigned shift,
                                             const unsigned* __restrict__ gh,
                                             const unsigned* __restrict__ dtot,
                                             const unsigned* __restrict__ nsyn,
                                             const unsigned* __restrict__ mskip,
                                             const int* __restrict__ sidx,
                                             const int* __restrict__ ridx,
                                             const float* __restrict__ rval,
                                             const float* __restrict__ grad,
                                             const unsigned* __restrict__ hcnt,
                                             unsigned* __restrict__ mout){
  unsigned Un = 0u, M = 0u;
  if (MODE == 1 || MODE == 2){
    Un = nsyn[0];
    M = mskip[0];
    if ((unsigned)blockIdx.x * TILE >= Un && M <= Un) return;
  }
  __shared__ unsigned wrun[4*256];
  __shared__ unsigned gput[256];
  __shared__ unsigned lw[4];
  __shared__ unsigned cutm;
  __shared__ uint64_t stage[TILE];       // 32 KB
  unsigned t = threadIdx.x, lane = t & 63u, w = t >> 6;
  wrun[t] = 0; wrun[256+t] = 0; wrun[512+t] = 0; wrun[768+t] = 0;
  __syncthreads();
  uint64_t ltm = (lane == 0) ? 0ull : (~0ull >> (64u - lane));
  uint64_t elems[WPT]; unsigned rnk[WPT]; unsigned dg[WPT];
  size_t base = (size_t)blockIdx.x * TILE + (size_t)w * (TILE/4);
  #pragma unroll
  for (int r = 0; r < WPT; r++){
    unsigned idx = (unsigned)(base + (size_t)r*64) + lane;
    uint64_t e;
    if (MODE == 3){
      e = make_elem(idx, sidx, ridx, rval, grad);
    } else if (MODE == 4){
      // sub-block within tile = w*4 + r/4; slot within sub-block = (r%4)*64+lane
      unsigned cnt = hcnt[blockIdx.x * 16u + (w << 2) + ((unsigned)r >> 2)];
      unsigned sl  = (((unsigned)r & 3u) << 6) + lane;
      e = (sl < cnt) ? in[idx] : SENT;
    } else if (MODE != 0){
      e = (idx < Un) ? in[idx] : SENT;
    } else {
      e = in[idx];
    }
    elems[r] = e;
    unsigned d = (unsigned)((e >> shift) & 0xFF);
    uint64_t m = ~0ull;
    #pragma unroll
    for (int b = 0; b < 8; b++){
      uint64_t bb = __ballot((d >> b) & 1u);
      m &= ((d >> b) & 1u) ? bb : ~bb;
    }
    unsigned rr   = (unsigned)__popcll(m & ltm);
    unsigned prev = wrun[w*256 + d];
    __builtin_amdgcn_wave_barrier();
    if (rr == 0) wrun[w*256 + d] = prev + (unsigned)__popcll(m);
    __builtin_amdgcn_wave_barrier();
    rnk[r] = prev + rr;
    dg[r]  = d;
  }
  __syncthreads();
  {
    unsigned d = t;
    unsigned c0 = wrun[d], c1 = wrun[256+d], c2 = wrun[512+d], c3 = wrun[768+d];
    unsigned cnt = c0 + c1 + c2 + c3;
    unsigned tot;
    unsigned ldig  = blockScanExcl(cnt, t, lw, &tot);       // local digit start
    unsigned tot2;
    unsigned dbase = blockScanExcl(dtot[d], t, lw, &tot2);  // global digit base
    if (MODE == 4){
      unsigned incl = dbase + dtot[d];                      // == k_cut arithmetic
      if (dbase < R_N && incl >= R_N) cutm = incl;
    }
    gput[d] = dbase + gh[d * NTILES + blockIdx.x] - ldig;
    wrun[d]       = ldig;
    wrun[256 + d] = ldig + c0;
    wrun[512 + d] = ldig + c0 + c1;
    wrun[768 + d] = ldig + c0 + c1 + c2;
  }
  __syncthreads();
  if (MODE == 4){
    M = cutm;
    if (blockIdx.x == 0u && t == 0u) mout[0] = M;           // for later kernels
  }
  #pragma unroll
  for (int r = 0; r < WPT; r++)
    stage[ wrun[w*256 + dg[r]] + rnk[r] ] = elems[r];
  __syncthreads();
  #pragma unroll
  for (int r = 0; r < WPT; r++){
    unsigned j = (unsigned)r * 256u + t;
    uint64_t e = stage[j];
    unsigned d = (unsigned)((e >> shift) & 0xFF);
    unsigned dest = gput[d] + j;
    if (MODE == 2){
      if (dest < R_N){
        uint32_t key = (uint32_t)(e >> 32);
        fout[2u*dest]        = (float)(key >> 12);
        fout[2u*dest + 1u]   = (float)(key & 4095u);
        fout[2u*R_N + dest]  = __uint_as_float(~(uint32_t)e);
      }
    } else if (MODE == 1 || MODE == 4){
      if (dest < M) out[dest] = e;
    } else {
      out[dest] = e;
    }
  }
}

__global__ __launch_bounds__(256) void k_scatter(const uint64_t* __restrict__ in,
                                                 uint64_t* __restrict__ out,
                                                 unsigned shift,
                                                 const unsigned* __restrict__ gh,
                                                 const unsigned* __restrict__ dtot){
  scatter_body<0>(in, out, nullptr, shift, gh, dtot, nullptr, nullptr,
                  nullptr, nullptr, nullptr, nullptr, nullptr, nullptr);
}

__global__ __launch_bounds__(256) void k_scatter_b(const int* __restrict__ sidx,
                                                   const int* __restrict__ ridx,
                                                   const float* __restrict__ rval,
                                                   const float* __restrict__ grad,
                                                   uint64_t* __restrict__ out,
                                                   unsigned shift,
                                                   const unsigned* __restrict__ gh,
                                                   const unsigned* __restrict__ dtot){
  scatter_body<3>(nullptr, out, nullptr, shift, gh, dtot, nullptr, nullptr,
                  sidx, ridx, rval, grad, nullptr, nullptr);
}

__global__ __launch_bounds__(256) void k_scatter_m(const uint64_t* __restrict__ in,
                                                   uint64_t* __restrict__ out,
                                                   unsigned shift,
                                                   const unsigned* __restrict__ gh,
                                                   const unsigned* __restrict__ dtot,
                                                   const unsigned* __restrict__ nsyn,
                                                   const unsigned* __restrict__ mskip){
  scatter_body<1>(in, out, nullptr, shift, gh, dtot, nsyn, mskip,
                  nullptr, nullptr, nullptr, nullptr, nullptr, nullptr);
}

__global__ __launch_bounds__(256) void k_scatter_mg(const uint64_t* __restrict__ in,
                                                    uint64_t* __restrict__ out,
                                                    unsigned shift,
                                                    const unsigned* __restrict__ gh,
                                                    const unsigned* __restrict__ dtot,
                                                    const unsigned* __restrict__ hcnt,
                                                    unsigned* __restrict__ mout){
  scatter_body<4>(in, out, nullptr, shift, gh, dtot, nullptr, nullptr,
                  nullptr, nullptr, nullptr, nullptr, hcnt, mout);
}

__global__ __launch_bounds__(256) void k_scatter_out(const uint64_t* __restrict__ in,
                                                     float* __restrict__ fout,
                                                     unsigned shift,
                                                     const unsigned* __restrict__ gh,
                                                     const unsigned* __restrict__ dtot,
                                                     const unsigned* __restrict__ nsyn){
  scatter_body<2>(in, nullptr, fout, shift, gh, dtot, nsyn, nsyn,
                  nullptr, nullptr, nullptr, nullptr, nullptr, nullptr);
}

// In-order segmented sum, GAPPED OUTPUT: one thread per element (proven shape;
// TLP hides the serial walks). Each block writes its candidates densely into
// its OWN 256-slot region out[b*256 + rank] and records hcnt[b] = count.
// No cross-block prefix needed -> headcount/scanheads kernels deleted.
// Candidate order (block asc, rank asc) remains globally key-ascending.
__global__ __launch_bounds__(256) void k_segsum2(const uint64_t* __restrict__ in,
                                                 uint64_t* __restrict__ out,
                                                 unsigned* __restrict__ hcnt){
  __shared__ unsigned wc[4], woffs[4];
  unsigned t = threadIdx.x, lane = t & 63u, w = t >> 6;
  size_t p = (size_t)blockIdx.x * 256 + t;
  uint64_t e0 = in[p];
  uint32_t k = (uint32_t)(e0 >> 32);
  bool head = ((p == 0) || ((uint32_t)(in[p-1] >> 32) != k)) && ((uint32_t)e0 != PAD_VAL);
  uint64_t m = __ballot(head);
  if (lane == 0) wc[w] = (unsigned)__popcll(m);
  __syncthreads();
  if (t == 0){
    unsigned a = 0;
    for (int i = 0; i < 4; i++){ woffs[i] = a; a += wc[i]; }
    hcnt[blockIdx.x] = a;
  }
  __syncthreads();
  if (head){
    uint64_t ltm = (lane == 0) ? 0ull : (~0ull >> (64u - lane));
    unsigned rank = (unsigned)__popcll(m & ltm);
    unsigned oidx = blockIdx.x * 256u + woffs[w] + rank;
    float s = __uint_as_float((uint32_t)e0);
    size_t q = p + 1;
    while (q < NPAD){
      uint64_t e = in[q];
      if ((uint32_t)(e >> 32) != k) break;
      uint32_t vb = (uint32_t)e;
      if (vb == PAD_VAL) break;
      s += __uint_as_float(vb);
      q++;
    }
    out[oidx] = ((uint64_t)k << 32) | (uint64_t)(uint32_t)(~__float_as_uint(s));
  }
}

extern "C" void kernel_launch(void* const* d_in, const int* in_sizes, int n_in,
                              void* d_out, int out_size, void* d_ws, size_t ws_size,
                              hipStream_t stream) {
  const int*   sidx = (const int*)d_in[0];
  const int*   ridx = (const int*)d_in[1];
  const float* rval = (const float*)d_in[2];
  const float* grad = (const float*)d_in[3];
  float* out = (float*)d_out;

  uint64_t* A0   = (uint64_t*)d_ws;                       // 35.3 MB
  uint64_t* A1   = A0 + NPAD;                             // 35.3 MB
  unsigned* gh   = (unsigned*)(A1 + NPAD);                // 1.1 MB
  unsigned* dtot = gh + 256 * NTILES;                     // 1 KB
  unsigned* hcnt = dtot + 256;                            // 67 KB
  unsigned* mvar = hcnt + NSB;                            // 4 B

  // Stable key sort: 24 bits, 3 x 8-bit passes. Pass 1 recomputes elements
  // from the raw inputs (no element-array build/read). inputs->A1->A0->A1.
  k_hist0    <<<NTILES, 256, 0, stream>>>(sidx, ridx, gh);
  k_scanrows <<<256,    256, 0, stream>>>(gh, dtot);
  k_scatter_b<<<NTILES, 256, 0, stream>>>(sidx, ridx, rval, grad, A1, 32, gh, dtot);
  k_hist     <<<NTILES, 256, 0, stream>>>(A1, 40, gh);
  k_scanrows <<<256,    256, 0, stream>>>(gh, dtot);
  k_scatter  <<<NTILES, 256, 0, stream>>>(A1, A0, 40, gh, dtot);
  k_hist     <<<NTILES, 256, 0, stream>>>(A0, 48, gh);
  k_scanrows <<<256,    256, 0, stream>>>(gh, dtot);
  k_scatter  <<<NTILES, 256, 0, stream>>>(A0, A1, 48, gh, dtot);

  // Coalesce, gapped: per-256-block dense candidates + hcnt. 1 dispatch,
  // no headcount read, no scanheads.
  k_segsum2<<<NSB, 256, 0, stream>>>(A1, A0, hcnt);

  // Select over the gapped layout: byte-24 histogram with per-block validity,
  // then gapped compact scatter with fused cut (M persisted to mvar).
  // Output A1[0, M) is dense.
  k_hist_syn2<<<NTILES, 256, 0, stream>>>(A0, 24, gh, hcnt);
  k_scanrows <<<256,    256, 0, stream>>>(gh, dtot);
  k_scatter_mg<<<NTILES, 256, 0, stream>>>(A0, A1, 24, gh, dtot, hcnt, mvar);

  // Stable value sort over only M elements: 4 x 8-bit LSD passes,
  // final pass fused with output emission. A1->A0->A1->A0->out.
  k_hist_syn <<<NTILES, 256, 0, stream>>>(A1, 0, gh, mvar);
  k_scanrows <<<256,    256, 0, stream>>>(gh, dtot);
  k_scatter_m<<<NTILES, 256, 0, stream>>>(A1, A0, 0, gh, dtot, mvar, mvar);
  k_hist_syn <<<NTILES, 256, 0, stream>>>(A0, 8, gh, mvar);
  k_scanrows <<<256,    256, 0, stream>>>(gh, dtot);
  k_scatter_m<<<NTILES, 256, 0, stream>>>(A0, A1, 8, gh, dtot, mvar, mvar);
  k_hist_syn <<<NTILES, 256, 0, stream>>>(A1, 16, gh, mvar);
  k_scanrows <<<256,    256, 0, stream>>>(gh, dtot);
  k_scatter_m<<<NTILES, 256, 0, stream>>>(A1, A0, 16, gh, dtot, mvar, mvar);
  k_hist_syn   <<<NTILES, 256, 0, stream>>>(A0, 24, gh, mvar);
  k_scanrows   <<<256,    256, 0, stream>>>(gh, dtot);
  k_scatter_out<<<NTILES, 256, 0, stream>>>(A0, out, 24, gh, dtot, mvar);
}